// Round 24
// baseline (150.961 us; speedup 1.0000x reference)
//
#include <hip/hip_runtime.h>
#include <cstdint>
#include <cstddef>

#define D_MODELX 1024
#define NUM_HEADX 16
#define D_KX 64
#define BBX 2
#define SSX 2048
#define M_TOK 4096   // B*S
#define MBYTE (1u << 20)

typedef __attribute__((ext_vector_type(8))) short short8;
typedef __attribute__((ext_vector_type(4))) short short4v;
typedef __attribute__((ext_vector_type(4))) float float4v;
typedef __attribute__((ext_vector_type(16))) float float16v;
typedef __attribute__((ext_vector_type(2))) unsigned uint2v;
typedef __attribute__((ext_vector_type(4))) unsigned uint4v;

__device__ __forceinline__ short f2bf(float f) {
  unsigned u = __builtin_bit_cast(unsigned, f);
  u = u + 0x7FFFu + ((u >> 16) & 1u);   // RNE
  return (short)(u >> 16);
}

// ---------------- mask -> bitmask ----------------
__global__ void mask_bits_kernel(const int* __restrict__ mask, unsigned* __restrict__ mbits) {
  int i = blockIdx.x * blockDim.x + threadIdx.x;   // over B*S*S = 8388608
  bool v = mask[i] != 0;
  unsigned long long bal = __ballot(v);
  int lane = threadIdx.x & 63;
  if (lane == 0)       mbits[i >> 5] = (unsigned)bal;
  else if (lane == 32) mbits[i >> 5] = (unsigned)(bal >> 32);
}

// ---------------- fp32 -> bf16 converts ----------------
__global__ void cvt7_kernel(const float* __restrict__ w0, const float* __restrict__ w1,
                            const float* __restrict__ w2, const float* __restrict__ w3,
                            short* __restrict__ o0, short* __restrict__ o1,
                            short* __restrict__ o2, short* __restrict__ o3,
                            const float* __restrict__ x0, const float* __restrict__ x1,
                            const float* __restrict__ x2,
                            short* __restrict__ xo0, short* __restrict__ xo1,
                            short* __restrict__ xo2) {
  int y = blockIdx.y;
  int i0 = blockIdx.x * blockDim.x + threadIdx.x;   // 0..262143
  if (y < 4) {
    const float* in = (y == 0) ? w0 : (y == 1) ? w1 : (y == 2) ? w2 : w3;
    short* out = (y == 0) ? o0 : (y == 1) ? o1 : (y == 2) ? o2 : o3;
    float4v v = ((const float4v*)in)[i0];
    short4v s;
    s[0] = f2bf(v[0]); s[1] = f2bf(v[1]); s[2] = f2bf(v[2]); s[3] = f2bf(v[3]);
    ((short4v*)out)[i0] = s;
  } else {
    const float* in = (y == 4) ? x0 : (y == 5) ? x1 : x2;
    short* out = (y == 4) ? xo0 : (y == 5) ? xo1 : xo2;
#pragma unroll
    for (int k = 0; k < 4; ++k) {
      int i = i0 + k * 262144;
      float4v v = ((const float4v*)in)[i];
      short4v s;
      s[0] = f2bf(v[0]); s[1] = f2bf(v[1]); s[2] = f2bf(v[2]); s[3] = f2bf(v[3]);
      ((short4v*)out)[i] = s;
    }
  }
}

// fallback-path converts
__global__ void cvt_w4_kernel(const float* __restrict__ w0, const float* __restrict__ w1,
                              const float* __restrict__ w2, const float* __restrict__ w3,
                              short* __restrict__ o0, short* __restrict__ o1,
                              short* __restrict__ o2, short* __restrict__ o3) {
  int z = blockIdx.y;
  const float* in = (z == 0) ? w0 : (z == 1) ? w1 : (z == 2) ? w2 : w3;
  short* out = (z == 0) ? o0 : (z == 1) ? o1 : (z == 2) ? o2 : o3;
  int i = blockIdx.x * blockDim.x + threadIdx.x;
  float4v v = ((const float4v*)in)[i];
  short4v s;
  s[0] = f2bf(v[0]); s[1] = f2bf(v[1]); s[2] = f2bf(v[2]); s[3] = f2bf(v[3]);
  ((short4v*)out)[i] = s;
}

__global__ void cvt_x3_kernel(const float* __restrict__ x0, const float* __restrict__ x1,
                              const float* __restrict__ x2,
                              short* __restrict__ o0, short* __restrict__ o1,
                              short* __restrict__ o2) {
  int z = blockIdx.y;
  const float* in = (z == 0) ? x0 : (z == 1) ? x1 : x2;
  short* out = (z == 0) ? o0 : (z == 1) ? o1 : o2;
  int i = blockIdx.x * blockDim.x + threadIdx.x;
  float4v v = ((const float4v*)in)[i];
  short4v s;
  s[0] = f2bf(v[0]); s[1] = f2bf(v[1]); s[2] = f2bf(v[2]); s[3] = f2bf(v[3]);
  ((short4v*)out)[i] = s;
}

// ---------------- GEMM body (64x128 tile, r20-proven) ----------------
#define GBK 64

__device__ __forceinline__ void gemm_body(const short* __restrict__ A,
                                          const short* __restrict__ Bw,
                                          const float* __restrict__ bias,
                                          float oscale, void* __restrict__ outp, int mode) {
  __shared__ short lds_a[64 * 64];     // 8KB
  __shared__ short lds_b[128 * 64];    // 16KB
  const int tid = threadIdx.x;
  const int lane = tid & 63;
  const int wn = tid >> 6;             // 4 waves across N
  const int bn = blockIdx.y >> 3;
  const int bm = (blockIdx.x << 3) | (blockIdx.y & 7);
  const int l15 = lane & 15, lg = lane >> 4;

  const int s_row = tid >> 3;
  const int s_cB = ((tid & 7) << 4) ^ ((s_row & 7) << 4);
  const short* Abase = A + (size_t)(bm * 64) * 1024 + (s_cB >> 1);
  const short* Bbase = Bw + (size_t)(bn * 128) * 1024 + (s_cB >> 1);

  const int xmask = (l15 & 7) << 4;
  const int a_b0 = l15 * 128 + ((lg * 16) ^ xmask);
  const int a_b1 = l15 * 128 + ((64 + lg * 16) ^ xmask);
  const int b_b0 = (wn * 32 + l15) * 128 + ((lg * 16) ^ xmask);
  const int b_b1 = (wn * 32 + l15) * 128 + ((64 + lg * 16) ^ xmask);

  float4v acc[4][2];
#pragma unroll
  for (int m = 0; m < 4; ++m)
#pragma unroll
    for (int n = 0; n < 2; ++n) acc[m][n] = (float4v){0.f, 0.f, 0.f, 0.f};

  for (int kt = 0; kt < 1024; kt += GBK) {
#pragma unroll
    for (int it = 0; it < 2; ++it) {
      int row = it * 32 + s_row;
      __builtin_amdgcn_global_load_lds(
          (const uint32_t*)(Abase + (size_t)row * 1024 + kt),
          (uint32_t*)(lds_a + (it * 256 + (tid >> 6) * 64) * 8), 16, 0, 0);
    }
#pragma unroll
    for (int it = 0; it < 4; ++it) {
      int row = it * 32 + s_row;
      __builtin_amdgcn_global_load_lds(
          (const uint32_t*)(Bbase + (size_t)row * 1024 + kt),
          (uint32_t*)(lds_b + (it * 256 + (tid >> 6) * 64) * 8), 16, 0, 0);
    }
    __syncthreads();

    short8 af[4][2];
#pragma unroll
    for (int m = 0; m < 4; ++m) {
      af[m][0] = *(const short8*)((const char*)lds_a + a_b0 + m * 2048);
      af[m][1] = *(const short8*)((const char*)lds_a + a_b1 + m * 2048);
    }
#pragma unroll
    for (int n = 0; n < 2; ++n) {
      short8 b0 = *(const short8*)((const char*)lds_b + b_b0 + n * 2048);
      short8 b1 = *(const short8*)((const char*)lds_b + b_b1 + n * 2048);
#pragma unroll
      for (int m = 0; m < 4; ++m) {
        acc[m][n] = __builtin_amdgcn_mfma_f32_16x16x32_bf16(af[m][0], b0, acc[m][n], 0, 0, 0);
        acc[m][n] = __builtin_amdgcn_mfma_f32_16x16x32_bf16(af[m][1], b1, acc[m][n], 0, 0, 0);
      }
    }
    __syncthreads();
  }

#pragma unroll
  for (int n = 0; n < 2; ++n) {
    int col = bn * 128 + wn * 32 + n * 16 + l15;
    float bv = bias[col];
#pragma unroll
    for (int m = 0; m < 4; ++m) {
      if (mode == 2) {
        int base_row = bm * 64 + m * 16 + lg * 4;
        int bidx = base_row >> 11, s = base_row & 2047;
        int h = col >> 6, d = col & 63;
        short4v sv;
#pragma unroll
        for (int r = 0; r < 4; ++r) sv[r] = f2bf(acc[m][n][r] + bv);
        *(short4v*)&((short*)outp)[(((size_t)(bidx * NUM_HEADX + h)) * D_KX + d) * SSX + s] = sv;
      } else {
#pragma unroll
        for (int r = 0; r < 4; ++r) {
          int row = bm * 64 + m * 16 + lg * 4 + r;
          float val = (acc[m][n][r] + bv) * oscale;
          if (mode == 0) {
            int bidx = row >> 11, s = row & 2047;
            int h = col >> 6, d = col & 63;
            ((short*)outp)[(((size_t)(bidx * NUM_HEADX + h)) * SSX + s) * D_KX + d] = f2bf(val);
          } else {
            ((float*)outp)[(size_t)row * D_MODELX + col] = val;
          }
        }
      }
    }
  }
}

__global__ __launch_bounds__(256) void gemm_qkv_kernel(
    const short* __restrict__ xq, const short* __restrict__ xk, const short* __restrict__ xv,
    const short* __restrict__ wq, const short* __restrict__ wk, const short* __restrict__ wv,
    const float* __restrict__ bq, const float* __restrict__ bk, const float* __restrict__ bv,
    short* __restrict__ qo, short* __restrict__ ko, short* __restrict__ vo, float qs) {
  int z = blockIdx.z;
  const short* A = (z == 0) ? xq : (z == 1) ? xk : xv;
  const short* W = (z == 0) ? wq : (z == 1) ? wk : wv;
  const float* bi = (z == 0) ? bq : (z == 1) ? bk : bv;
  void* out = (z == 0) ? (void*)qo : (z == 1) ? (void*)ko : (void*)vo;
  float os = (z == 0) ? qs : 1.0f;
  int mode = (z == 2) ? 2 : 0;
  gemm_body(A, W, bi, os, out, mode);
}

__global__ __launch_bounds__(256) void gemm_one_kernel(const short* __restrict__ A,
                                                       const short* __restrict__ W,
                                                       const float* __restrict__ bias,
                                                       float os, void* __restrict__ out, int mode) {
  gemm_body(A, W, bias, os, out, mode);
}

// ---------------- output GEMM: 64x64 tile, fp32 out (r21-proven) ----------------
__global__ __launch_bounds__(256) void gemm_o_kernel(const short* __restrict__ A,
                                                     const short* __restrict__ W,
                                                     const float* __restrict__ bias,
                                                     float* __restrict__ out) {
  __shared__ short lds_a[64 * 64];     // 8KB
  __shared__ short lds_b[64 * 64];     // 8KB
  const int tid = threadIdx.x;
  const int lane = tid & 63;
  const int wn = tid >> 6;             // 4 waves x 16 cols
  const int bn = blockIdx.y >> 3;
  const int bm = (blockIdx.x << 3) | (blockIdx.y & 7);
  const int l15 = lane & 15, lg = lane >> 4;

  const int s_row = tid >> 3;
  const int s_cB = ((tid & 7) << 4) ^ ((s_row & 7) << 4);
  const short* Abase = A + (size_t)(bm * 64) * 1024 + (s_cB >> 1);
  const short* Bbase = W + (size_t)(bn * 64) * 1024 + (s_cB >> 1);

  const int xmask = (l15 & 7) << 4;
  const int a_b0 = l15 * 128 + ((lg * 16) ^ xmask);
  const int a_b1 = l15 * 128 + ((64 + lg * 16) ^ xmask);
  const int b_b0 = (wn * 16 + l15) * 128 + ((lg * 16) ^ xmask);
  const int b_b1 = (wn * 16 + l15) * 128 + ((64 + lg * 16) ^ xmask);

  float4v acc[4];
#pragma unroll
  for (int m = 0; m < 4; ++m) acc[m] = (float4v){0.f, 0.f, 0.f, 0.f};

  for (int kt = 0; kt < 1024; kt += GBK) {
#pragma unroll
    for (int it = 0; it < 2; ++it) {
      int row = it * 32 + s_row;
      __builtin_amdgcn_global_load_lds(
          (const uint32_t*)(Abase + (size_t)row * 1024 + kt),
          (uint32_t*)(lds_a + (it * 256 + (tid >> 6) * 64) * 8), 16, 0, 0);
      __builtin_amdgcn_global_load_lds(
          (const uint32_t*)(Bbase + (size_t)row * 1024 + kt),
          (uint32_t*)(lds_b + (it * 256 + (tid >> 6) * 64) * 8), 16, 0, 0);
    }
    __syncthreads();

    short8 b0 = *(const short8*)((const char*)lds_b + b_b0);
    short8 b1 = *(const short8*)((const char*)lds_b + b_b1);
#pragma unroll
    for (int m = 0; m < 4; ++m) {
      short8 a0 = *(const short8*)((const char*)lds_a + a_b0 + m * 2048);
      short8 a1 = *(const short8*)((const char*)lds_a + a_b1 + m * 2048);
      acc[m] = __builtin_amdgcn_mfma_f32_16x16x32_bf16(a0, b0, acc[m], 0, 0, 0);
      acc[m] = __builtin_amdgcn_mfma_f32_16x16x32_bf16(a1, b1, acc[m], 0, 0, 0);
    }
    __syncthreads();
  }

  int col = bn * 64 + wn * 16 + l15;
  float bv = bias[col];
#pragma unroll
  for (int m = 0; m < 4; ++m)
#pragma unroll
    for (int r = 0; r < 4; ++r) {
      int row = bm * 64 + m * 16 + lg * 4 + r;
      out[(size_t)row * D_MODELX + col] = acc[m][r] + bv;
    }
}

// ---------------- flash attention: 8-wave blocks, QBLK=256 ----------------
// grid: (B*H)*(S/256)=256 x-blocks x NSPLIT, 512 threads (8 waves x 32 q).
// Same per-wave structure as r23 (32x32 MFMA, in-reg P via cvt_pk+permlane, setprio,
// no max tracking, lgkm-only barrier). Changes: K/V staging amortized over 256 q-rows
// (one 16B chunk/thread/array), grid 512 blocks = exactly 2/CU fully co-resident
// (zero tail), 16 waves/CU for barrier-stall amortization.
__global__ __launch_bounds__(512, 2) void attn_kernel(const short* __restrict__ q_ws,
                                                      const short* __restrict__ k_ws,
                                                      const short* __restrict__ vT_ws,
                                                      const unsigned* __restrict__ mbits,
                                                      short* __restrict__ attn_ws,
                                                      short* __restrict__ opart,
                                                      float* __restrict__ lpart) {
  __shared__ short k_lds[2][4096];
  __shared__ short vT_lds[2][4096];

  const int tid = threadIdx.x;
  const int lane = tid & 63;
  const int w = tid >> 6;              // 0..7
  const int l31 = lane & 31, hi = lane >> 5;
  // XCD-aware bijective swizzle: 256 x-blocks = 8 XCDs x 32
  const int bid0 = blockIdx.x;
  const int bid = ((bid0 & 7) << 5) | (bid0 >> 3);
  const int qt = bid & 7;              // S/256 = 8 q-tiles
  const int bh = bid >> 3;             // 0..31
  const int b = bh >> 4;
  const int h = bh & 15;
  const int z = blockIdx.z;
  const int nsplit = gridDim.z;
  const int nt = (SSX / 64) / nsplit;
  const int kb0 = z * nt * 64;

  const int qrow = qt * 256 + w * 32;
  const int q = qrow + l31;

  const int xm = (lane & 7) << 4;
  int rd[4];
#pragma unroll
  for (int j = 0; j < 4; ++j) rd[j] = l31 * 128 + ((j * 32 + hi * 16) ^ xm);
  char* kbase = (char*)k_lds;
  char* vbase = (char*)vT_lds;

  // staging: 512 threads x 16B = one 64x64 tile per array; srow 0..63, 8 thr/row
  const int srow = tid >> 3;
  const int scolS = (tid & 7) * 8;     // shorts
  const int st0 = srow * 128 + ((scolS * 2) ^ ((srow & 7) << 4));

  const short* kp = k_ws + (size_t)bh * SSX * D_KX + (size_t)srow * D_KX + scolS;
  const short* vp = vT_ws + (size_t)bh * D_KX * SSX + (size_t)srow * SSX + scolS;

  short8 qf[4];
#pragma unroll
  for (int ds = 0; ds < 4; ++ds)
    qf[ds] = *(const short8*)(q_ws + ((size_t)bh * SSX + q) * D_KX + ds * 16 + hi * 8);

  float16v acc[2];
#pragma unroll
  for (int db = 0; db < 2; ++db)
#pragma unroll
    for (int i = 0; i < 16; ++i) acc[db][i] = 0.f;
  float l_own = 0.f;

  short8 kr0, vr0;
  auto loadt = [&](int kb) {
    kr0 = *(const short8*)(kp + (size_t)kb * D_KX);
    vr0 = *(const short8*)(vp + kb);
  };
  auto storet = [&](int BUF) {
    *(short8*)(kbase + BUF + st0) = kr0;
    *(short8*)(vbase + BUF + st0) = vr0;
  };

  const unsigned* mrow = mbits + ((size_t)b * SSX + q) * (SSX / 32) + (kb0 >> 5);
  unsigned long long mw = *(const unsigned long long*)mrow, mwn = 0;

  loadt(kb0);
  storet(0);
  loadt(kb0 + 64);
  __syncthreads();

  auto step = [&](int t, int CURB, int NXTB) {
    unsigned long long shv = mw >> (hi * 4);

    auto do_kb = [&](const float16v& s, int kb, int CURB_) {
      unsigned wvm = (kb == 0) ? (unsigned)shv : (unsigned)(shv >> 32);
      unsigned cw[8];
      float ls = 0.f;
#pragma unroll
      for (int qd = 0; qd < 4; ++qd) {
        float pv_[4];
#pragma unroll
        for (int r = 0; r < 4; ++r) {
          float e = __builtin_amdgcn_exp2f(s[qd * 4 + r]);
          e = ((wvm >> (qd * 8 + r)) & 1u) ? e : 0.f;
          ls += e;
          pv_[r] = e;
        }
        unsigned u0, u1;
        asm("v_cvt_pk_bf16_f32 %0, %1, %2" : "=v"(u0) : "v"(pv_[0]), "v"(pv_[1]));
        asm("v_cvt_pk_bf16_f32 %0, %1, %2" : "=v"(u1) : "v"(pv_[2]), "v"(pv_[3]));
        cw[qd * 2] = u0;
        cw[qd * 2 + 1] = u1;
      }
      l_own += ls;
#pragma unroll
      for (int g = 0; g < 2; ++g) {
        unsigned a0 = cw[2 * g * 2],     b0 = cw[(2 * g + 1) * 2];
        unsigned a1 = cw[2 * g * 2 + 1], b1 = cw[(2 * g + 1) * 2 + 1];
        asm("v_permlane32_swap_b32 %0, %1" : "+v"(a0), "+v"(b0));
        asm("v_permlane32_swap_b32 %0, %1" : "+v"(a1), "+v"(b1));
        short8 Bf = __builtin_bit_cast(short8, (uint4v){a0, a1, b0, b1});
        __builtin_amdgcn_s_setprio(1);
#pragma unroll
        for (int db = 0; db < 2; ++db) {
          short8 vf = *(const short8*)(vbase + CURB_ + db * 4096 + rd[kb * 2 + g]);
          acc[db] = __builtin_amdgcn_mfma_f32_32x32x16_bf16(vf, Bf, acc[db], 0, 0, 0);
        }
        __builtin_amdgcn_s_setprio(0);
      }
    };

    float16v s0, s1;
#pragma unroll
    for (int i = 0; i < 16; ++i) { s0[i] = 0.f; s1[i] = 0.f; }
    __builtin_amdgcn_s_setprio(1);
#pragma unroll
    for (int ds = 0; ds < 4; ++ds) {
      short8 ka = *(const short8*)(kbase + CURB + rd[ds]);
      short8 kb_ = *(const short8*)(kbase + CURB + 4096 + rd[ds]);
      s0 = __builtin_amdgcn_mfma_f32_32x32x16_bf16(ka, qf[ds], s0, 0, 0, 0);
      s1 = __builtin_amdgcn_mfma_f32_32x32x16_bf16(kb_, qf[ds], s1, 0, 0, 0);
    }
    __builtin_amdgcn_s_setprio(0);

    if (t < nt - 1) storet(NXTB);
    if (t < nt - 2) loadt(kb0 + (t + 2) * 64);
    if (t < nt - 1) mwn = *(const unsigned long long*)(mrow + 2 * (t + 1));

    do_kb(s0, 0, CURB);
    do_kb(s1, 1, CURB);

    asm volatile("s_waitcnt lgkmcnt(0)" ::: "memory");
    __builtin_amdgcn_s_barrier();
    mw = mwn;
  };

  for (int t2 = 0; t2 < nt / 2; ++t2) {
    step(2 * t2, 0, 8192);
    step(2 * t2 + 1, 8192, 0);
  }

  float lp = l_own + __shfl_xor(l_own, 32);
  if (nsplit == 1) {
    float inv = 1.0f / lp;
    size_t ttok = (size_t)b * SSX + q;
#pragma unroll
    for (int db = 0; db < 2; ++db)
#pragma unroll
      for (int qd = 0; qd < 4; ++qd) {
        short4v sv;
#pragma unroll
        for (int r = 0; r < 4; ++r) sv[r] = f2bf(acc[db][qd * 4 + r] * inv);
        *(short4v*)&attn_ws[ttok * D_MODELX + h * 64 + db * 32 + qd * 8 + hi * 4] = sv;
      }
  } else {
    size_t rowp = ((size_t)z * 32 + bh) * SSX + q;
    if (hi == 0) lpart[rowp] = lp;
#pragma unroll
    for (int db = 0; db < 2; ++db)
#pragma unroll
      for (int qd = 0; qd < 4; ++qd) {
        short4v sv;
#pragma unroll
        for (int r = 0; r < 4; ++r) sv[r] = f2bf(acc[db][qd * 4 + r]);
        *(short4v*)&opart[rowp * D_KX + db * 32 + qd * 8 + hi * 4] = sv;
      }
  }
}

// ---------------- split combine: attn_ws = (O0+O1)/(l0+l1) ----------------
__global__ void combine_kernel(const short* __restrict__ opart, const float* __restrict__ lpart,
                               short* __restrict__ attn_ws) {
  int gtid = blockIdx.x * blockDim.x + threadIdx.x;   // 524288 threads
  int row = gtid >> 3;
  int dc = (gtid & 7) * 8;
  int bh = row >> 11, s = row & 2047;
  int b = bh >> 4, h = bh & 15;
  float inv = 1.0f / (lpart[row] + lpart[row + 32 * SSX]);
  short8 o0 = *(const short8*)&opart[(size_t)row * D_KX + dc];
  short8 o1 = *(const short8*)&opart[((size_t)row + 32 * SSX) * D_KX + dc];
  short8 sv;
#pragma unroll
  for (int j = 0; j < 8; ++j) {
    float f0 = __builtin_bit_cast(float, ((unsigned)(unsigned short)o0[j]) << 16);
    float f1 = __builtin_bit_cast(float, ((unsigned)(unsigned short)o1[j]) << 16);
    sv[j] = f2bf((f0 + f1) * inv);
  }
  *(short8*)&attn_ws[(((size_t)b * SSX + s) * D_MODELX) + h * 64 + dc] = sv;
}

// ---------------- launcher ----------------
extern "C" void kernel_launch(void* const* d_in, const int* in_sizes, int n_in,
                              void* d_out, int out_size, void* d_ws, size_t ws_size,
                              hipStream_t stream) {
  const float* x_q = (const float*)d_in[0];
  const float* x_k = (const float*)d_in[1];
  const float* x_v = (const float*)d_in[2];
  const int*   mask = (const int*)d_in[3];
  const float* Wq = (const float*)d_in[4];
  const float* bq = (const float*)d_in[5];
  const float* Wk = (const float*)d_in[6];
  const float* bk = (const float*)d_in[7];
  const float* Wv = (const float*)d_in[8];
  const float* bv = (const float*)d_in[9];
  const float* Wo = (const float*)d_in[10];
  const float* bo = (const float*)d_in[11];

  const float QSCALE = 0.125f * 1.44269504089f;

  char* ws = (char*)d_ws;
  short* q_ws  = (short*)(ws + 0 * MBYTE);
  short* k_ws  = (short*)(ws + 8 * MBYTE);
  short* vT_ws = (short*)(ws + 16 * MBYTE);

  dim3 ggrid(8, 64);   // 64x128 tiles (fallback / qkv planes)

  if (ws_size >= (size_t)56 * MBYTE) {
    short* wq_bf = (short*)(ws + 24 * MBYTE);
    short* wk_bf = (short*)(ws + 26 * MBYTE);
    short* wv_bf = (short*)(ws + 28 * MBYTE);
    short* wo_bf = (short*)(ws + 30 * MBYTE);
    short* xq_bf = (short*)(ws + 32 * MBYTE);
    short* xk_bf = (short*)(ws + 40 * MBYTE);
    short* xv_bf = (short*)(ws + 48 * MBYTE);
    // after QKV gemm: wq/wk/wv and xq/xk/xv are dead
    unsigned* mbits = (unsigned*)(ws + 24 * MBYTE);      // 1MB, aliases wq_bf
    float* lpart    = (float*)(ws + 25 * MBYTE);         // 512KB
    short* attn_ws  = (short*)(ws + 32 * MBYTE);         // 8MB, aliases xq_bf
    short* opart    = (short*)(ws + 40 * MBYTE);         // 16MB, aliases xk_bf+xv_bf

    cvt7_kernel<<<dim3(1024, 7), 256, 0, stream>>>(Wq, Wk, Wv, Wo, wq_bf, wk_bf, wv_bf, wo_bf,
                                                   x_q, x_k, x_v, xq_bf, xk_bf, xv_bf);

    dim3 qkvgrid(8, 64, 3);
    gemm_qkv_kernel<<<qkvgrid, 256, 0, stream>>>(xq_bf, xk_bf, xv_bf, wq_bf, wk_bf, wv_bf,
                                                 bq, bk, bv, q_ws, k_ws, vT_ws, QSCALE);

    mask_bits_kernel<<<(BBX * SSX * SSX) / 256, 256, 0, stream>>>(mask, mbits);

    dim3 agrid(BBX * NUM_HEADX * (SSX / 256), 1, 2);
    attn_kernel<<<agrid, 512, 0, stream>>>(q_ws, k_ws, vT_ws, mbits, attn_ws, opart, lpart);
    combine_kernel<<<2048, 256, 0, stream>>>(opart, lpart, attn_ws);

    gemm_o_kernel<<<dim3(8, 128), 256, 0, stream>>>(attn_ws, wo_bf, bo, (float*)d_out);
  } else {
    // sequential low-footprint path (35 MB), single split
    unsigned* mbits = (unsigned*)(ws + 24 * MBYTE);
    short* w_bf = (short*)(ws + 25 * MBYTE);
    short* x_bf = (short*)(ws + 27 * MBYTE);
    short* attn_ws = (short*)(ws + 27 * MBYTE);  // aliases x_bf

    mask_bits_kernel<<<(BBX * SSX * SSX) / 256, 256, 0, stream>>>(mask, mbits);

    cvt_w4_kernel<<<dim3(1024, 1), 256, 0, stream>>>(Wq, Wq, Wq, Wq, w_bf, w_bf, w_bf, w_bf);
    cvt_x3_kernel<<<dim3(4096, 1), 256, 0, stream>>>(x_q, x_q, x_q, x_bf, x_bf, x_bf);
    gemm_one_kernel<<<ggrid, 256, 0, stream>>>(x_bf, w_bf, bq, QSCALE, q_ws, 0);

    cvt_w4_kernel<<<dim3(1024, 1), 256, 0, stream>>>(Wk, Wk, Wk, Wk, w_bf, w_bf, w_bf, w_bf);
    cvt_x3_kernel<<<dim3(4096, 1), 256, 0, stream>>>(x_k, x_k, x_k, x_bf, x_bf, x_bf);
    gemm_one_kernel<<<ggrid, 256, 0, stream>>>(x_bf, w_bf, bk, 1.0f, k_ws, 0);

    cvt_w4_kernel<<<dim3(1024, 1), 256, 0, stream>>>(Wv, Wv, Wv, Wv, w_bf, w_bf, w_bf, w_bf);
    cvt_x3_kernel<<<dim3(4096, 1), 256, 0, stream>>>(x_v, x_v, x_v, x_bf, x_bf, x_bf);
    gemm_one_kernel<<<ggrid, 256, 0, stream>>>(x_bf, w_bf, bv, 1.0f, vT_ws, 2);

    dim3 agrid(BBX * NUM_HEADX * (SSX / 256), 1, 1);
    attn_kernel<<<agrid, 512, 0, stream>>>(q_ws, k_ws, vT_ws, mbits, attn_ws, nullptr, nullptr);

    cvt_w4_kernel<<<dim3(1024, 1), 256, 0, stream>>>(Wo, Wo, Wo, Wo, w_bf, w_bf, w_bf, w_bf);
    gemm_one_kernel<<<ggrid, 256, 0, stream>>>(attn_ws, w_bf, bo, 1.0f, d_out, 1);
  }
}

// Round 25
// 143.513 us; speedup vs baseline: 1.0519x; 1.0519x over previous
//
#include <hip/hip_runtime.h>
#include <cstdint>
#include <cstddef>

#define D_MODELX 1024
#define NUM_HEADX 16
#define D_KX 64
#define BBX 2
#define SSX 2048
#define M_TOK 4096   // B*S
#define MBYTE (1u << 20)

typedef __attribute__((ext_vector_type(8))) short short8;
typedef __attribute__((ext_vector_type(4))) short short4v;
typedef __attribute__((ext_vector_type(4))) float float4v;
typedef __attribute__((ext_vector_type(16))) float float16v;
typedef __attribute__((ext_vector_type(2))) unsigned uint2v;
typedef __attribute__((ext_vector_type(4))) unsigned uint4v;

__device__ __forceinline__ short f2bf(float f) {
  unsigned u = __builtin_bit_cast(unsigned, f);
  u = u + 0x7FFFu + ((u >> 16) & 1u);   // RNE
  return (short)(u >> 16);
}

// ---------------- mask -> bitmask ----------------
__global__ void mask_bits_kernel(const int* __restrict__ mask, unsigned* __restrict__ mbits) {
  int i = blockIdx.x * blockDim.x + threadIdx.x;   // over B*S*S = 8388608
  bool v = mask[i] != 0;
  unsigned long long bal = __ballot(v);
  int lane = threadIdx.x & 63;
  if (lane == 0)       mbits[i >> 5] = (unsigned)bal;
  else if (lane == 32) mbits[i >> 5] = (unsigned)(bal >> 32);
}

// ---------------- fp32 -> bf16 converts ----------------
__global__ void cvt7_kernel(const float* __restrict__ w0, const float* __restrict__ w1,
                            const float* __restrict__ w2, const float* __restrict__ w3,
                            short* __restrict__ o0, short* __restrict__ o1,
                            short* __restrict__ o2, short* __restrict__ o3,
                            const float* __restrict__ x0, const float* __restrict__ x1,
                            const float* __restrict__ x2,
                            short* __restrict__ xo0, short* __restrict__ xo1,
                            short* __restrict__ xo2) {
  int y = blockIdx.y;
  int i0 = blockIdx.x * blockDim.x + threadIdx.x;   // 0..262143
  if (y < 4) {
    const float* in = (y == 0) ? w0 : (y == 1) ? w1 : (y == 2) ? w2 : w3;
    short* out = (y == 0) ? o0 : (y == 1) ? o1 : (y == 2) ? o2 : o3;
    float4v v = ((const float4v*)in)[i0];
    short4v s;
    s[0] = f2bf(v[0]); s[1] = f2bf(v[1]); s[2] = f2bf(v[2]); s[3] = f2bf(v[3]);
    ((short4v*)out)[i0] = s;
  } else {
    const float* in = (y == 4) ? x0 : (y == 5) ? x1 : x2;
    short* out = (y == 4) ? xo0 : (y == 5) ? xo1 : xo2;
#pragma unroll
    for (int k = 0; k < 4; ++k) {
      int i = i0 + k * 262144;
      float4v v = ((const float4v*)in)[i];
      short4v s;
      s[0] = f2bf(v[0]); s[1] = f2bf(v[1]); s[2] = f2bf(v[2]); s[3] = f2bf(v[3]);
      ((short4v*)out)[i] = s;
    }
  }
}

// fallback-path converts
__global__ void cvt_w4_kernel(const float* __restrict__ w0, const float* __restrict__ w1,
                              const float* __restrict__ w2, const float* __restrict__ w3,
                              short* __restrict__ o0, short* __restrict__ o1,
                              short* __restrict__ o2, short* __restrict__ o3) {
  int z = blockIdx.y;
  const float* in = (z == 0) ? w0 : (z == 1) ? w1 : (z == 2) ? w2 : w3;
  short* out = (z == 0) ? o0 : (z == 1) ? o1 : (z == 2) ? o2 : o3;
  int i = blockIdx.x * blockDim.x + threadIdx.x;
  float4v v = ((const float4v*)in)[i];
  short4v s;
  s[0] = f2bf(v[0]); s[1] = f2bf(v[1]); s[2] = f2bf(v[2]); s[3] = f2bf(v[3]);
  ((short4v*)out)[i] = s;
}

__global__ void cvt_x3_kernel(const float* __restrict__ x0, const float* __restrict__ x1,
                              const float* __restrict__ x2,
                              short* __restrict__ o0, short* __restrict__ o1,
                              short* __restrict__ o2) {
  int z = blockIdx.y;
  const float* in = (z == 0) ? x0 : (z == 1) ? x1 : x2;
  short* out = (z == 0) ? o0 : (z == 1) ? o1 : o2;
  int i = blockIdx.x * blockDim.x + threadIdx.x;
  float4v v = ((const float4v*)in)[i];
  short4v s;
  s[0] = f2bf(v[0]); s[1] = f2bf(v[1]); s[2] = f2bf(v[2]); s[3] = f2bf(v[3]);
  ((short4v*)out)[i] = s;
}

// ---------------- GEMM body (64x128 tile, r20-proven) ----------------
#define GBK 64

__device__ __forceinline__ void gemm_body(const short* __restrict__ A,
                                          const short* __restrict__ Bw,
                                          const float* __restrict__ bias,
                                          float oscale, void* __restrict__ outp, int mode) {
  __shared__ short lds_a[64 * 64];     // 8KB
  __shared__ short lds_b[128 * 64];    // 16KB
  const int tid = threadIdx.x;
  const int lane = tid & 63;
  const int wn = tid >> 6;             // 4 waves across N
  const int bn = blockIdx.y >> 3;
  const int bm = (blockIdx.x << 3) | (blockIdx.y & 7);
  const int l15 = lane & 15, lg = lane >> 4;

  const int s_row = tid >> 3;
  const int s_cB = ((tid & 7) << 4) ^ ((s_row & 7) << 4);
  const short* Abase = A + (size_t)(bm * 64) * 1024 + (s_cB >> 1);
  const short* Bbase = Bw + (size_t)(bn * 128) * 1024 + (s_cB >> 1);

  const int xmask = (l15 & 7) << 4;
  const int a_b0 = l15 * 128 + ((lg * 16) ^ xmask);
  const int a_b1 = l15 * 128 + ((64 + lg * 16) ^ xmask);
  const int b_b0 = (wn * 32 + l15) * 128 + ((lg * 16) ^ xmask);
  const int b_b1 = (wn * 32 + l15) * 128 + ((64 + lg * 16) ^ xmask);

  float4v acc[4][2];
#pragma unroll
  for (int m = 0; m < 4; ++m)
#pragma unroll
    for (int n = 0; n < 2; ++n) acc[m][n] = (float4v){0.f, 0.f, 0.f, 0.f};

  for (int kt = 0; kt < 1024; kt += GBK) {
#pragma unroll
    for (int it = 0; it < 2; ++it) {
      int row = it * 32 + s_row;
      __builtin_amdgcn_global_load_lds(
          (const uint32_t*)(Abase + (size_t)row * 1024 + kt),
          (uint32_t*)(lds_a + (it * 256 + (tid >> 6) * 64) * 8), 16, 0, 0);
    }
#pragma unroll
    for (int it = 0; it < 4; ++it) {
      int row = it * 32 + s_row;
      __builtin_amdgcn_global_load_lds(
          (const uint32_t*)(Bbase + (size_t)row * 1024 + kt),
          (uint32_t*)(lds_b + (it * 256 + (tid >> 6) * 64) * 8), 16, 0, 0);
    }
    __syncthreads();

    short8 af[4][2];
#pragma unroll
    for (int m = 0; m < 4; ++m) {
      af[m][0] = *(const short8*)((const char*)lds_a + a_b0 + m * 2048);
      af[m][1] = *(const short8*)((const char*)lds_a + a_b1 + m * 2048);
    }
#pragma unroll
    for (int n = 0; n < 2; ++n) {
      short8 b0 = *(const short8*)((const char*)lds_b + b_b0 + n * 2048);
      short8 b1 = *(const short8*)((const char*)lds_b + b_b1 + n * 2048);
#pragma unroll
      for (int m = 0; m < 4; ++m) {
        acc[m][n] = __builtin_amdgcn_mfma_f32_16x16x32_bf16(af[m][0], b0, acc[m][n], 0, 0, 0);
        acc[m][n] = __builtin_amdgcn_mfma_f32_16x16x32_bf16(af[m][1], b1, acc[m][n], 0, 0, 0);
      }
    }
    __syncthreads();
  }

#pragma unroll
  for (int n = 0; n < 2; ++n) {
    int col = bn * 128 + wn * 32 + n * 16 + l15;
    float bv = bias[col];
#pragma unroll
    for (int m = 0; m < 4; ++m) {
      if (mode == 2) {
        int base_row = bm * 64 + m * 16 + lg * 4;
        int bidx = base_row >> 11, s = base_row & 2047;
        int h = col >> 6, d = col & 63;
        short4v sv;
#pragma unroll
        for (int r = 0; r < 4; ++r) sv[r] = f2bf(acc[m][n][r] + bv);
        *(short4v*)&((short*)outp)[(((size_t)(bidx * NUM_HEADX + h)) * D_KX + d) * SSX + s] = sv;
      } else {
#pragma unroll
        for (int r = 0; r < 4; ++r) {
          int row = bm * 64 + m * 16 + lg * 4 + r;
          float val = (acc[m][n][r] + bv) * oscale;
          if (mode == 0) {
            int bidx = row >> 11, s = row & 2047;
            int h = col >> 6, d = col & 63;
            ((short*)outp)[(((size_t)(bidx * NUM_HEADX + h)) * SSX + s) * D_KX + d] = f2bf(val);
          } else {
            ((float*)outp)[(size_t)row * D_MODELX + col] = val;
          }
        }
      }
    }
  }
}

__global__ __launch_bounds__(256) void gemm_qkv_kernel(
    const short* __restrict__ xq, const short* __restrict__ xk, const short* __restrict__ xv,
    const short* __restrict__ wq, const short* __restrict__ wk, const short* __restrict__ wv,
    const float* __restrict__ bq, const float* __restrict__ bk, const float* __restrict__ bv,
    short* __restrict__ qo, short* __restrict__ ko, short* __restrict__ vo, float qs) {
  int z = blockIdx.z;
  const short* A = (z == 0) ? xq : (z == 1) ? xk : xv;
  const short* W = (z == 0) ? wq : (z == 1) ? wk : wv;
  const float* bi = (z == 0) ? bq : (z == 1) ? bk : bv;
  void* out = (z == 0) ? (void*)qo : (z == 1) ? (void*)ko : (void*)vo;
  float os = (z == 0) ? qs : 1.0f;
  int mode = (z == 2) ? 2 : 0;
  gemm_body(A, W, bi, os, out, mode);
}

__global__ __launch_bounds__(256) void gemm_one_kernel(const short* __restrict__ A,
                                                       const short* __restrict__ W,
                                                       const float* __restrict__ bias,
                                                       float os, void* __restrict__ out, int mode) {
  gemm_body(A, W, bias, os, out, mode);
}

// ---------------- output GEMM: 64x64 tile, fp32 out (r21-proven) ----------------
__global__ __launch_bounds__(256) void gemm_o_kernel(const short* __restrict__ A,
                                                     const short* __restrict__ W,
                                                     const float* __restrict__ bias,
                                                     float* __restrict__ out) {
  __shared__ short lds_a[64 * 64];     // 8KB
  __shared__ short lds_b[64 * 64];     // 8KB
  const int tid = threadIdx.x;
  const int lane = tid & 63;
  const int wn = tid >> 6;             // 4 waves x 16 cols
  const int bn = blockIdx.y >> 3;
  const int bm = (blockIdx.x << 3) | (blockIdx.y & 7);
  const int l15 = lane & 15, lg = lane >> 4;

  const int s_row = tid >> 3;
  const int s_cB = ((tid & 7) << 4) ^ ((s_row & 7) << 4);
  const short* Abase = A + (size_t)(bm * 64) * 1024 + (s_cB >> 1);
  const short* Bbase = W + (size_t)(bn * 64) * 1024 + (s_cB >> 1);

  const int xmask = (l15 & 7) << 4;
  const int a_b0 = l15 * 128 + ((lg * 16) ^ xmask);
  const int a_b1 = l15 * 128 + ((64 + lg * 16) ^ xmask);
  const int b_b0 = (wn * 16 + l15) * 128 + ((lg * 16) ^ xmask);
  const int b_b1 = (wn * 16 + l15) * 128 + ((64 + lg * 16) ^ xmask);

  float4v acc[4];
#pragma unroll
  for (int m = 0; m < 4; ++m) acc[m] = (float4v){0.f, 0.f, 0.f, 0.f};

  for (int kt = 0; kt < 1024; kt += GBK) {
#pragma unroll
    for (int it = 0; it < 2; ++it) {
      int row = it * 32 + s_row;
      __builtin_amdgcn_global_load_lds(
          (const uint32_t*)(Abase + (size_t)row * 1024 + kt),
          (uint32_t*)(lds_a + (it * 256 + (tid >> 6) * 64) * 8), 16, 0, 0);
      __builtin_amdgcn_global_load_lds(
          (const uint32_t*)(Bbase + (size_t)row * 1024 + kt),
          (uint32_t*)(lds_b + (it * 256 + (tid >> 6) * 64) * 8), 16, 0, 0);
    }
    __syncthreads();

    short8 b0 = *(const short8*)((const char*)lds_b + b_b0);
    short8 b1 = *(const short8*)((const char*)lds_b + b_b1);
#pragma unroll
    for (int m = 0; m < 4; ++m) {
      short8 a0 = *(const short8*)((const char*)lds_a + a_b0 + m * 2048);
      short8 a1 = *(const short8*)((const char*)lds_a + a_b1 + m * 2048);
      acc[m] = __builtin_amdgcn_mfma_f32_16x16x32_bf16(a0, b0, acc[m], 0, 0, 0);
      acc[m] = __builtin_amdgcn_mfma_f32_16x16x32_bf16(a1, b1, acc[m], 0, 0, 0);
    }
    __syncthreads();
  }

  int col = bn * 64 + wn * 16 + l15;
  float bv = bias[col];
#pragma unroll
  for (int m = 0; m < 4; ++m)
#pragma unroll
    for (int r = 0; r < 4; ++r) {
      int row = bm * 64 + m * 16 + lg * 4 + r;
      out[(size_t)row * D_MODELX + col] = acc[m][r] + bv;
    }
}

// ---------------- flash attention (r23 best-known config, verbatim) ----------------
// 4 waves x 32 q (QBLK=128), 32x32 MFMA swapped-operand, in-register P via
// cvt_pk + v_permlane32_swap, no max tracking (log2-domain bounded scores),
// setprio around MFMA clusters (r22 A/B: +7.6us when removed), lgkm-only barrier,
// KV-split 2 via grid.z, __launch_bounds__(256,2) -> VGPR 80, no spill.
__global__ __launch_bounds__(256, 2) void attn_kernel(const short* __restrict__ q_ws,
                                                      const short* __restrict__ k_ws,
                                                      const short* __restrict__ vT_ws,
                                                      const unsigned* __restrict__ mbits,
                                                      short* __restrict__ attn_ws,
                                                      short* __restrict__ opart,
                                                      float* __restrict__ lpart) {
  __shared__ short k_lds[2][4096];
  __shared__ short vT_lds[2][4096];

  const int tid = threadIdx.x;
  const int lane = tid & 63;
  const int w = tid >> 6;
  const int l31 = lane & 31, hi = lane >> 5;
  const int bid0 = blockIdx.x;
  const int bid = ((bid0 & 7) << 6) | (bid0 >> 3);
  const int qt = bid & 15;
  const int bh = bid >> 4;
  const int b = bh >> 4;
  const int h = bh & 15;
  const int z = blockIdx.z;
  const int nsplit = gridDim.z;
  const int nt = (SSX / 64) / nsplit;
  const int kb0 = z * nt * 64;

  const int qrow = qt * 128 + w * 32;
  const int q = qrow + l31;

  const int xm = (lane & 7) << 4;
  int rd[4];
#pragma unroll
  for (int j = 0; j < 4; ++j) rd[j] = l31 * 128 + ((j * 32 + hi * 16) ^ xm);
  char* kbase = (char*)k_lds;
  char* vbase = (char*)vT_lds;

  const int srow = tid >> 2;
  const int scolS = (tid & 3) * 16;
  const int st0 = srow * 128 + ((scolS * 2) ^ ((srow & 7) << 4));
  const int st1 = srow * 128 + ((scolS * 2 + 16) ^ ((srow & 7) << 4));

  const short* kp = k_ws + (size_t)bh * SSX * D_KX + (size_t)srow * D_KX + scolS;
  const short* vp = vT_ws + (size_t)bh * D_KX * SSX + (size_t)srow * SSX + scolS;

  short8 qf[4];
#pragma unroll
  for (int ds = 0; ds < 4; ++ds)
    qf[ds] = *(const short8*)(q_ws + ((size_t)bh * SSX + q) * D_KX + ds * 16 + hi * 8);

  float16v acc[2];
#pragma unroll
  for (int db = 0; db < 2; ++db)
#pragma unroll
    for (int i = 0; i < 16; ++i) acc[db][i] = 0.f;
  float l_own = 0.f;

  short8 kr0, kr1, vr0, vr1;
  auto loadt = [&](int kb) {
    const short* kq = kp + (size_t)kb * D_KX;
    kr0 = *(const short8*)kq;
    kr1 = *(const short8*)(kq + 8);
    const short* vq = vp + kb;
    vr0 = *(const short8*)vq;
    vr1 = *(const short8*)(vq + 8);
  };
  auto storet = [&](int BUF) {
    *(short8*)(kbase + BUF + st0) = kr0;
    *(short8*)(kbase + BUF + st1) = kr1;
    *(short8*)(vbase + BUF + st0) = vr0;
    *(short8*)(vbase + BUF + st1) = vr1;
  };

  const unsigned* mrow = mbits + ((size_t)b * SSX + q) * (SSX / 32) + (kb0 >> 5);
  unsigned long long mw = *(const unsigned long long*)mrow, mwn = 0;

  loadt(kb0);
  storet(0);
  loadt(kb0 + 64);
  __syncthreads();

  auto step = [&](int t, int CURB, int NXTB) {
    unsigned long long shv = mw >> (hi * 4);

    auto do_kb = [&](const float16v& s, int kb, int CURB_) {
      unsigned wvm = (kb == 0) ? (unsigned)shv : (unsigned)(shv >> 32);
      unsigned cw[8];
      float ls = 0.f;
#pragma unroll
      for (int qd = 0; qd < 4; ++qd) {
        float pv_[4];
#pragma unroll
        for (int r = 0; r < 4; ++r) {
          float e = __builtin_amdgcn_exp2f(s[qd * 4 + r]);
          e = ((wvm >> (qd * 8 + r)) & 1u) ? e : 0.f;
          ls += e;
          pv_[r] = e;
        }
        unsigned u0, u1;
        asm("v_cvt_pk_bf16_f32 %0, %1, %2" : "=v"(u0) : "v"(pv_[0]), "v"(pv_[1]));
        asm("v_cvt_pk_bf16_f32 %0, %1, %2" : "=v"(u1) : "v"(pv_[2]), "v"(pv_[3]));
        cw[qd * 2] = u0;
        cw[qd * 2 + 1] = u1;
      }
      l_own += ls;
#pragma unroll
      for (int g = 0; g < 2; ++g) {
        unsigned a0 = cw[2 * g * 2],     b0 = cw[(2 * g + 1) * 2];
        unsigned a1 = cw[2 * g * 2 + 1], b1 = cw[(2 * g + 1) * 2 + 1];
        asm("v_permlane32_swap_b32 %0, %1" : "+v"(a0), "+v"(b0));
        asm("v_permlane32_swap_b32 %0, %1" : "+v"(a1), "+v"(b1));
        short8 Bf = __builtin_bit_cast(short8, (uint4v){a0, a1, b0, b1});
        __builtin_amdgcn_s_setprio(1);
#pragma unroll
        for (int db = 0; db < 2; ++db) {
          short8 vf = *(const short8*)(vbase + CURB_ + db * 4096 + rd[kb * 2 + g]);
          acc[db] = __builtin_amdgcn_mfma_f32_32x32x16_bf16(vf, Bf, acc[db], 0, 0, 0);
        }
        __builtin_amdgcn_s_setprio(0);
      }
    };

    float16v s0, s1;
#pragma unroll
    for (int i = 0; i < 16; ++i) { s0[i] = 0.f; s1[i] = 0.f; }
    __builtin_amdgcn_s_setprio(1);
#pragma unroll
    for (int ds = 0; ds < 4; ++ds) {
      short8 ka = *(const short8*)(kbase + CURB + rd[ds]);
      short8 kb_ = *(const short8*)(kbase + CURB + 4096 + rd[ds]);
      s0 = __builtin_amdgcn_mfma_f32_32x32x16_bf16(ka, qf[ds], s0, 0, 0, 0);
      s1 = __builtin_amdgcn_mfma_f32_32x32x16_bf16(kb_, qf[ds], s1, 0, 0, 0);
    }
    __builtin_amdgcn_s_setprio(0);

    if (t < nt - 1) storet(NXTB);
    if (t < nt - 2) loadt(kb0 + (t + 2) * 64);
    if (t < nt - 1) mwn = *(const unsigned long long*)(mrow + 2 * (t + 1));

    do_kb(s0, 0, CURB);
    do_kb(s1, 1, CURB);

    asm volatile("s_waitcnt lgkmcnt(0)" ::: "memory");
    __builtin_amdgcn_s_barrier();
    mw = mwn;
  };

  for (int t2 = 0; t2 < nt / 2; ++t2) {
    step(2 * t2, 0, 8192);
    step(2 * t2 + 1, 8192, 0);
  }

  float lp = l_own + __shfl_xor(l_own, 32);
  if (nsplit == 1) {
    float inv = 1.0f / lp;
    size_t ttok = (size_t)b * SSX + q;
#pragma unroll
    for (int db = 0; db < 2; ++db)
#pragma unroll
      for (int qd = 0; qd < 4; ++qd) {
        short4v sv;
#pragma unroll
        for (int r = 0; r < 4; ++r) sv[r] = f2bf(acc[db][qd * 4 + r] * inv);
        *(short4v*)&attn_ws[ttok * D_MODELX + h * 64 + db * 32 + qd * 8 + hi * 4] = sv;
      }
  } else {
    size_t rowp = ((size_t)z * 32 + bh) * SSX + q;
    if (hi == 0) lpart[rowp] = lp;
#pragma unroll
    for (int db = 0; db < 2; ++db)
#pragma unroll
      for (int qd = 0; qd < 4; ++qd) {
        short4v sv;
#pragma unroll
        for (int r = 0; r < 4; ++r) sv[r] = f2bf(acc[db][qd * 4 + r]);
        *(short4v*)&opart[rowp * D_KX + db * 32 + qd * 8 + hi * 4] = sv;
      }
  }
}

// ---------------- split combine: attn_ws = (O0+O1)/(l0+l1) ----------------
__global__ void combine_kernel(const short* __restrict__ opart, const float* __restrict__ lpart,
                               short* __restrict__ attn_ws) {
  int gtid = blockIdx.x * blockDim.x + threadIdx.x;   // 524288 threads
  int row = gtid >> 3;
  int dc = (gtid & 7) * 8;
  int bh = row >> 11, s = row & 2047;
  int b = bh >> 4, h = bh & 15;
  float inv = 1.0f / (lpart[row] + lpart[row + 32 * SSX]);
  short8 o0 = *(const short8*)&opart[(size_t)row * D_KX + dc];
  short8 o1 = *(const short8*)&opart[((size_t)row + 32 * SSX) * D_KX + dc];
  short8 sv;
#pragma unroll
  for (int j = 0; j < 8; ++j) {
    float f0 = __builtin_bit_cast(float, ((unsigned)(unsigned short)o0[j]) << 16);
    float f1 = __builtin_bit_cast(float, ((unsigned)(unsigned short)o1[j]) << 16);
    sv[j] = f2bf((f0 + f1) * inv);
  }
  *(short8*)&attn_ws[(((size_t)b * SSX + s) * D_MODELX) + h * 64 + dc] = sv;
}

// ---------------- launcher ----------------
extern "C" void kernel_launch(void* const* d_in, const int* in_sizes, int n_in,
                              void* d_out, int out_size, void* d_ws, size_t ws_size,
                              hipStream_t stream) {
  const float* x_q = (const float*)d_in[0];
  const float* x_k = (const float*)d_in[1];
  const float* x_v = (const float*)d_in[2];
  const int*   mask = (const int*)d_in[3];
  const float* Wq = (const float*)d_in[4];
  const float* bq = (const float*)d_in[5];
  const float* Wk = (const float*)d_in[6];
  const float* bk = (const float*)d_in[7];
  const float* Wv = (const float*)d_in[8];
  const float* bv = (const float*)d_in[9];
  const float* Wo = (const float*)d_in[10];
  const float* bo = (const float*)d_in[11];

  const float QSCALE = 0.125f * 1.44269504089f;

  char* ws = (char*)d_ws;
  short* q_ws  = (short*)(ws + 0 * MBYTE);
  short* k_ws  = (short*)(ws + 8 * MBYTE);
  short* vT_ws = (short*)(ws + 16 * MBYTE);

  dim3 ggrid(8, 64);   // 64x128 tiles (fallback / qkv planes)

  if (ws_size >= (size_t)56 * MBYTE) {
    short* wq_bf = (short*)(ws + 24 * MBYTE);
    short* wk_bf = (short*)(ws + 26 * MBYTE);
    short* wv_bf = (short*)(ws + 28 * MBYTE);
    short* wo_bf = (short*)(ws + 30 * MBYTE);
    short* xq_bf = (short*)(ws + 32 * MBYTE);
    short* xk_bf = (short*)(ws + 40 * MBYTE);
    short* xv_bf = (short*)(ws + 48 * MBYTE);
    // after QKV gemm: wq/wk/wv and xq/xk/xv are dead
    unsigned* mbits = (unsigned*)(ws + 24 * MBYTE);      // 1MB, aliases wq_bf
    float* lpart    = (float*)(ws + 25 * MBYTE);         // 512KB
    short* attn_ws  = (short*)(ws + 32 * MBYTE);         // 8MB, aliases xq_bf
    short* opart    = (short*)(ws + 40 * MBYTE);         // 16MB, aliases xk_bf+xv_bf

    cvt7_kernel<<<dim3(1024, 7), 256, 0, stream>>>(Wq, Wk, Wv, Wo, wq_bf, wk_bf, wv_bf, wo_bf,
                                                   x_q, x_k, x_v, xq_bf, xk_bf, xv_bf);

    dim3 qkvgrid(8, 64, 3);
    gemm_qkv_kernel<<<qkvgrid, 256, 0, stream>>>(xq_bf, xk_bf, xv_bf, wq_bf, wk_bf, wv_bf,
                                                 bq, bk, bv, q_ws, k_ws, vT_ws, QSCALE);

    mask_bits_kernel<<<(BBX * SSX * SSX) / 256, 256, 0, stream>>>(mask, mbits);

    dim3 agrid(BBX * NUM_HEADX * (SSX / 128), 1, 2);
    attn_kernel<<<agrid, 256, 0, stream>>>(q_ws, k_ws, vT_ws, mbits, attn_ws, opart, lpart);
    combine_kernel<<<2048, 256, 0, stream>>>(opart, lpart, attn_ws);

    gemm_o_kernel<<<dim3(8, 128), 256, 0, stream>>>(attn_ws, wo_bf, bo, (float*)d_out);
  } else {
    // sequential low-footprint path (35 MB), single split
    unsigned* mbits = (unsigned*)(ws + 24 * MBYTE);
    short* w_bf = (short*)(ws + 25 * MBYTE);
    short* x_bf = (short*)(ws + 27 * MBYTE);
    short* attn_ws = (short*)(ws + 27 * MBYTE);  // aliases x_bf

    mask_bits_kernel<<<(BBX * SSX * SSX) / 256, 256, 0, stream>>>(mask, mbits);

    cvt_w4_kernel<<<dim3(1024, 1), 256, 0, stream>>>(Wq, Wq, Wq, Wq, w_bf, w_bf, w_bf, w_bf);
    cvt_x3_kernel<<<dim3(4096, 1), 256, 0, stream>>>(x_q, x_q, x_q, x_bf, x_bf, x_bf);
    gemm_one_kernel<<<ggrid, 256, 0, stream>>>(x_bf, w_bf, bq, QSCALE, q_ws, 0);

    cvt_w4_kernel<<<dim3(1024, 1), 256, 0, stream>>>(Wk, Wk, Wk, Wk, w_bf, w_bf, w_bf, w_bf);
    cvt_x3_kernel<<<dim3(4096, 1), 256, 0, stream>>>(x_k, x_k, x_k, x_bf, x_bf, x_bf);
    gemm_one_kernel<<<ggrid, 256, 0, stream>>>(x_bf, w_bf, bk, 1.0f, k_ws, 0);

    cvt_w4_kernel<<<dim3(1024, 1), 256, 0, stream>>>(Wv, Wv, Wv, Wv, w_bf, w_bf, w_bf, w_bf);
    cvt_x3_kernel<<<dim3(4096, 1), 256, 0, stream>>>(x_v, x_v, x_v, x_bf, x_bf, x_bf);
    gemm_one_kernel<<<ggrid, 256, 0, stream>>>(x_bf, w_bf, bv, 1.0f, vT_ws, 2);

    dim3 agrid(BBX * NUM_HEADX * (SSX / 128), 1, 1);
    attn_kernel<<<agrid, 256, 0, stream>>>(q_ws, k_ws, vT_ws, mbits, attn_ws, nullptr, nullptr);

    cvt_w4_kernel<<<dim3(1024, 1), 256, 0, stream>>>(Wo, Wo, Wo, Wo, w_bf, w_bf, w_bf, w_bf);
    gemm_one_kernel<<<ggrid, 256, 0, stream>>>(attn_ws, w_bf, bo, 1.0f, d_out, 1);
  }
}